// Round 1
// baseline (49.217 us; speedup 1.0000x reference)
//
#include <hip/hip_runtime.h>
#include <hip/hip_bf16.h>
#include <stdint.h>

// Problem: costh[B,CK] = (x/||x||_row) @ (W/||W||_col),  x:[B,D] f32, W:[D,CK] f32
// B=512, D=512, CK=5994*3=17982. Output f32.

#define D_DIM 512
#define BM 128
#define BN 128
#define GRAN 8                    // bf16 elements per 16B granule
#define NG (D_DIM / GRAN)         // 64 granules along D
#define KSTEP 32                  // K per MFMA
#define NSTEPS (D_DIM / KSTEP)    // 16
#define TILE_BYTES (NG * BM * 16) // 131072 bytes per 128-row tile

typedef __bf16 bf16x8 __attribute__((ext_vector_type(8)));
typedef float f32x4 __attribute__((ext_vector_type(4)));

__device__ __forceinline__ unsigned short f2bf(float f) {
  union { float f; unsigned int u; } v; v.f = f;
  unsigned int u = v.u;
  u += 0x7fffu + ((u >> 16) & 1u);   // round-to-nearest-even
  return (unsigned short)(u >> 16);
}

__device__ __forceinline__ void load_lds16(const void* g, void* l) {
  __builtin_amdgcn_global_load_lds(
      (__attribute__((address_space(1))) void*)(g),
      (__attribute__((address_space(3))) void*)(l), 16, 0, 0);
}

// ---------------- kernel 1: column inverse norms of W ----------------
// grid: ceil(CK/64) blocks x 256 threads. 4 threads per column.
__global__ void wnorm_kernel(const float* __restrict__ W, float* __restrict__ invn, int CK) {
  __shared__ float red[256];
  const int t = threadIdx.x;
  const int n0 = blockIdx.x * 64;
  const int col = n0 + (t & 63);
  const int q = t >> 6;                       // wave id = row quarter
  const int ccl = col < CK ? col : CK - 1;
  const float* p = W + (size_t)q * 128 * CK + ccl;
  float acc = 0.f;
  const bool valid = col < CK;
#pragma unroll 8
  for (int i = 0; i < 128; ++i) {
    float v = p[(size_t)i * CK];
    v = valid ? v : 0.f;
    acc += v * v;
  }
  red[t] = acc;
  __syncthreads();
  if (t < 64) {
    float s = red[t] + red[t + 64] + red[t + 128] + red[t + 192];
    if (n0 + t < CK) invn[n0 + t] = 1.f / fmaxf(sqrtf(s), 1e-8f);
  }
}

// ---------------- kernel 2: x row norms -> An tiled bf16 ----------------
// grid: B blocks x 64 threads. An[mtile][g][r][8] = xn[mtile*128+r][8g+e]
__global__ void xnorm_kernel(const float* __restrict__ x, unsigned short* __restrict__ An) {
  const int m = blockIdx.x;
  const int t = threadIdx.x;                  // = granule g
  const float* xr = x + (size_t)m * D_DIM + t * 8;
  float4 a = *(const float4*)(xr);
  float4 b = *(const float4*)(xr + 4);
  float s = a.x * a.x + a.y * a.y + a.z * a.z + a.w * a.w +
            b.x * b.x + b.y * b.y + b.z * b.z + b.w * b.w;
#pragma unroll
  for (int off = 32; off; off >>= 1) s += __shfl_xor(s, off, 64);
  const float inv = 1.f / fmaxf(sqrtf(s), 1e-8f);
  ushort4 o0, o1;
  o0.x = f2bf(a.x * inv); o0.y = f2bf(a.y * inv); o0.z = f2bf(a.z * inv); o0.w = f2bf(a.w * inv);
  o1.x = f2bf(b.x * inv); o1.y = f2bf(b.y * inv); o1.z = f2bf(b.z * inv); o1.w = f2bf(b.w * inv);
  const int mtile = m >> 7, r = m & 127;
  unsigned short* dst = An + (size_t)mtile * (TILE_BYTES / 2) + (size_t)t * (BM * 8) + r * 8;
  *(ushort4*)dst = o0;
  *(ushort4*)(dst + 4) = o1;
}

// ---------------- kernel 3: W scale + transpose -> Wt tiled bf16 ----------------
// grid: (ntiles, 8) x 256 threads. Wt[ntile][g][r][e] = W[8g+e][ntile*128+r]*invn
__global__ void wtrans_kernel(const float* __restrict__ W, const float* __restrict__ invn,
                              unsigned short* __restrict__ Wt, int CK) {
  const int t = threadIdx.x;
  const int ntile = blockIdx.x;
  const int gb = blockIdx.y;                  // granule block: g = gb*8 + i
  const int r = t >> 1;                       // 0..127 (output column index n - n0)
  const int h = t & 1;                        // which 4-element half of the granule
  const int n = ntile * BN + r;
  const bool valid = n < CK;
  const float inv = valid ? invn[n] : 0.f;    // pad columns -> zeros
  const int ncl = valid ? n : CK - 1;
  unsigned short* outBase = Wt + (size_t)ntile * (TILE_BYTES / 2);
#pragma unroll
  for (int i = 0; i < 8; ++i) {
    const int g = gb * 8 + i;
    const int d0 = g * 8 + h * 4;
    float v0 = W[(size_t)(d0 + 0) * CK + ncl] * inv;
    float v1 = W[(size_t)(d0 + 1) * CK + ncl] * inv;
    float v2 = W[(size_t)(d0 + 2) * CK + ncl] * inv;
    float v3 = W[(size_t)(d0 + 3) * CK + ncl] * inv;
    ushort4 o;
    o.x = f2bf(v0); o.y = f2bf(v1); o.z = f2bf(v2); o.w = f2bf(v3);
    *(ushort4*)(outBase + (size_t)g * (BM * 8) + r * 8 + h * 4) = o;
  }
}

// ---------------- kernel 4: bf16 MFMA GEMM ----------------
// grid: (ntiles, B/128) x 256 threads (4 waves). 128x128 tile, BK=32.
__global__ __launch_bounds__(256, 2) void gemm_kernel(const unsigned short* __restrict__ An,
                                                      const unsigned short* __restrict__ Wt,
                                                      float* __restrict__ out, int CK) {
  __shared__ __attribute__((aligned(16))) unsigned char lds[16384];
  unsigned char* ldsA = lds;
  unsigned char* ldsB = lds + 8192;
  const int ntile = blockIdx.x, mtile = blockIdx.y;
  const int t = threadIdx.x;
  const int lane = t & 63, w = t >> 6;
  const int wm = w >> 1, wn = w & 1;          // wave -> 64x64 quadrant
  const int lrow = lane & 15;                 // fragment row/col
  const int g = lane >> 4;                    // k-granule within K-step

  const unsigned char* srcA = (const unsigned char*)An + (size_t)mtile * TILE_BYTES;
  const unsigned char* srcB = (const unsigned char*)Wt + (size_t)ntile * TILE_BYTES;

  f32x4 acc[4][4] = {};

  for (int kt = 0; kt < NSTEPS; ++kt) {
    const size_t koff = (size_t)kt * 8192;
#pragma unroll
    for (int c = 0; c < 2; ++c) {
      const int off = w * 2048 + c * 1024;
      load_lds16(srcA + koff + off + lane * 16, ldsA + off);
      load_lds16(srcB + koff + off + lane * 16, ldsB + off);
    }
    __syncthreads();
    bf16x8 afrag[4], bfrag[4];
#pragma unroll
    for (int i = 0; i < 4; ++i) {
      afrag[i] = *(const bf16x8*)(ldsA + g * 2048 + (wm * 64 + i * 16 + lrow) * 16);
      bfrag[i] = *(const bf16x8*)(ldsB + g * 2048 + (wn * 64 + i * 16 + lrow) * 16);
    }
#pragma unroll
    for (int i = 0; i < 4; ++i)
#pragma unroll
      for (int j = 0; j < 4; ++j)
        acc[i][j] = __builtin_amdgcn_mfma_f32_16x16x32_bf16(afrag[i], bfrag[j], acc[i][j], 0, 0, 0);
    __syncthreads();
  }

  // epilogue: C layout col=lane&15, row=(lane>>4)*4+reg
#pragma unroll
  for (int j = 0; j < 4; ++j) {
    const int col = ntile * 128 + wn * 64 + j * 16 + lrow;
    if (col < CK) {
#pragma unroll
      for (int i = 0; i < 4; ++i) {
#pragma unroll
        for (int jj = 0; jj < 4; ++jj) {
          const int row = mtile * 128 + wm * 64 + i * 16 + g * 4 + jj;
          out[(size_t)row * CK + col] = acc[i][j][jj];
        }
      }
    }
  }
}

extern "C" void kernel_launch(void* const* d_in, const int* in_sizes, int n_in,
                              void* d_out, int out_size, void* d_ws, size_t ws_size,
                              hipStream_t stream) {
  const float* x = (const float*)d_in[0];
  const float* W = (const float*)d_in[1];
  float* out = (float*)d_out;
  const int Bn = in_sizes[0] / D_DIM;   // 512
  const int CK = in_sizes[1] / D_DIM;   // 17982
  const int ntiles = (CK + BN - 1) / BN; // 141
  const int mtiles = Bn / BM;            // 4

  unsigned char* ws = (unsigned char*)d_ws;
  float* invn = (float*)ws;                                        // 72KB used
  unsigned short* An = (unsigned short*)(ws + 131072);             // 512KB
  unsigned short* Wt = (unsigned short*)(ws + 131072 + (size_t)mtiles * TILE_BYTES);

  hipLaunchKernelGGL(wnorm_kernel, dim3((CK + 63) / 64), dim3(256), 0, stream, W, invn, CK);
  hipLaunchKernelGGL(xnorm_kernel, dim3(Bn), dim3(64), 0, stream, x, An);
  hipLaunchKernelGGL(wtrans_kernel, dim3(ntiles, 8), dim3(256), 0, stream, W, invn, Wt, CK);
  hipLaunchKernelGGL(gemm_kernel, dim3(ntiles, mtiles), dim3(256), 0, stream, An, Wt, out, CK);
}

// Round 2
// 42.889 us; speedup vs baseline: 1.1475x; 1.1475x over previous
//
#include <hip/hip_runtime.h>
#include <hip/hip_bf16.h>
#include <stdint.h>

// costh[B,CK] = (x/||x||_row) @ (W/||W||_col),  x:[B,D] f32, W:[D,CK] f32
// B=512, D=512, CK=5994*3=17982. Output f32.
// W is read from HBM exactly once (transpose+convert+partial sumsq fused);
// column inv-norms are finalized in the GEMM epilogue.

#define D_DIM 512
#define BM 128
#define BN 128
#define NG (D_DIM / 8)            // 64 granules along D
#define NSTEPS (D_DIM / 32)       // 16 K-steps
#define TILE_BYTES (NG * BM * 16) // 131072 bytes per 128-row tile

typedef __bf16 bf16x8 __attribute__((ext_vector_type(8)));
typedef float f32x4 __attribute__((ext_vector_type(4)));

__device__ __forceinline__ unsigned short f2bf(float f) {
  union { float f; unsigned int u; } v; v.f = f;
  unsigned int u = v.u;
  u += 0x7fffu + ((u >> 16) & 1u);   // RNE
  return (unsigned short)(u >> 16);
}

__device__ __forceinline__ void load_lds16(const void* g, void* l) {
  __builtin_amdgcn_global_load_lds(
      (__attribute__((address_space(1))) void*)(g),
      (__attribute__((address_space(3))) void*)(l), 16, 0, 0);
}

// ---------------- kernel 1: x row norms -> An tiled bf16 (normalized) ----------------
__global__ void xnorm_kernel(const float* __restrict__ x, unsigned short* __restrict__ An) {
  const int m = blockIdx.x;
  const int t = threadIdx.x;                  // = granule g
  const float* xr = x + (size_t)m * D_DIM + t * 8;
  float4 a = *(const float4*)(xr);
  float4 b = *(const float4*)(xr + 4);
  float s = a.x * a.x + a.y * a.y + a.z * a.z + a.w * a.w +
            b.x * b.x + b.y * b.y + b.z * b.z + b.w * b.w;
#pragma unroll
  for (int off = 32; off; off >>= 1) s += __shfl_xor(s, off, 64);
  const float inv = 1.f / fmaxf(sqrtf(s), 1e-8f);
  ushort4 o0, o1;
  o0.x = f2bf(a.x * inv); o0.y = f2bf(a.y * inv); o0.z = f2bf(a.z * inv); o0.w = f2bf(a.w * inv);
  o1.x = f2bf(b.x * inv); o1.y = f2bf(b.y * inv); o1.z = f2bf(b.z * inv); o1.w = f2bf(b.w * inv);
  const int mtile = m >> 7, r = m & 127;
  unsigned short* dst = An + (size_t)mtile * (TILE_BYTES / 2) + (size_t)t * (BM * 8) + r * 8;
  *(ushort4*)dst = o0;
  *(ushort4*)(dst + 4) = o1;
}

// ---------------- kernel 2: W -> Wt tiled bf16 (UNscaled) + partial column sumsq ----------------
// grid: (ntiles, 8) x 256. Block handles 64 d-rows x 128 cols. W read ONCE, coalesced float4.
__global__ void wtrans2_kernel(const float* __restrict__ W, unsigned short* __restrict__ Wt,
                               float* __restrict__ partial, int CK, int NT128) {
  __shared__ unsigned short tile[64][128];    // 16 KB: tile[d_local][n_local]
  __shared__ float red[256 * 4];              // 4 KB per-thread 4-col partials
  const int t = threadIdx.x;
  const int ntile = blockIdx.x, gb = blockIdx.y;
  const int n0 = ntile * BN;
  const int cq = t & 31;                      // column quad: cols cq*4..cq*4+3
  const int dr = t >> 5;                      // base d row 0..7
  const int d_base = gb * 64;
  float ss0 = 0.f, ss1 = 0.f, ss2 = 0.f, ss3 = 0.f;

  if (n0 + BN <= CK) {
#pragma unroll
    for (int i = 0; i < 8; ++i) {
      const int dl = dr + i * 8;
      float4 v = *(const float4*)(W + (size_t)(d_base + dl) * CK + n0 + cq * 4);
      ss0 += v.x * v.x; ss1 += v.y * v.y; ss2 += v.z * v.z; ss3 += v.w * v.w;
      ushort4 o; o.x = f2bf(v.x); o.y = f2bf(v.y); o.z = f2bf(v.z); o.w = f2bf(v.w);
      *(ushort4*)&tile[dl][cq * 4] = o;
    }
  } else {
#pragma unroll
    for (int i = 0; i < 8; ++i) {
      const int dl = dr + i * 8;
      float v[4];
#pragma unroll
      for (int e = 0; e < 4; ++e) {
        int n = n0 + cq * 4 + e;
        v[e] = W[(size_t)(d_base + dl) * CK + (n < CK ? n : CK - 1)];
      }
      ss0 += v[0] * v[0]; ss1 += v[1] * v[1]; ss2 += v[2] * v[2]; ss3 += v[3] * v[3];
      ushort4 o; o.x = f2bf(v[0]); o.y = f2bf(v[1]); o.z = f2bf(v[2]); o.w = f2bf(v[3]);
      *(ushort4*)&tile[dl][cq * 4] = o;
    }
  }
  red[t * 4 + 0] = ss0; red[t * 4 + 1] = ss1; red[t * 4 + 2] = ss2; red[t * 4 + 3] = ss3;
  __syncthreads();

  // per-column partial sumsq: thread t<128 owns column t (red index k*128 + t, conflict-free)
  if (t < 128) {
    float s = 0.f;
#pragma unroll
    for (int k = 0; k < 8; ++k) s += red[k * 128 + t];
    partial[(size_t)gb * NT128 + n0 + t] = s;
  }

  // granule writes: idx -> (g = idx>>7 local granule, r = idx&127 col); coalesced 16B stores
  unsigned short* outBase = Wt + (size_t)ntile * (TILE_BYTES / 2);
#pragma unroll
  for (int i = 0; i < 4; ++i) {
    const int idx = t + 256 * i;
    const int g = idx >> 7, r = idx & 127;
    ushort4 o0, o1;
    o0.x = tile[g * 8 + 0][r]; o0.y = tile[g * 8 + 1][r];
    o0.z = tile[g * 8 + 2][r]; o0.w = tile[g * 8 + 3][r];
    o1.x = tile[g * 8 + 4][r]; o1.y = tile[g * 8 + 5][r];
    o1.z = tile[g * 8 + 6][r]; o1.w = tile[g * 8 + 7][r];
    unsigned short* dst = outBase + (size_t)(gb * 8 + g) * (BM * 8) + r * 8;
    *(ushort4*)dst = o0;
    *(ushort4*)(dst + 4) = o1;
  }
}

// ---------------- kernel 3: bf16 MFMA GEMM + winv epilogue ----------------
__global__ __launch_bounds__(256, 2) void gemm_kernel(const unsigned short* __restrict__ An,
                                                      const unsigned short* __restrict__ Wt,
                                                      const float* __restrict__ partial,
                                                      float* __restrict__ out, int CK, int NT128) {
  __shared__ __attribute__((aligned(16))) unsigned char lds[16384];
  unsigned char* ldsA = lds;
  unsigned char* ldsB = lds + 8192;
  const int ntile = blockIdx.x, mtile = blockIdx.y;
  const int t = threadIdx.x;
  const int lane = t & 63, w = t >> 6;
  const int wm = w >> 1, wn = w & 1;          // wave -> 64x64 quadrant
  const int lrow = lane & 15;
  const int g = lane >> 4;                    // k-granule within K-step

  const unsigned char* srcA = (const unsigned char*)An + (size_t)mtile * TILE_BYTES;
  const unsigned char* srcB = (const unsigned char*)Wt + (size_t)ntile * TILE_BYTES;

  f32x4 acc[4][4] = {};

  for (int kt = 0; kt < NSTEPS; ++kt) {
    const size_t koff = (size_t)kt * 8192;
#pragma unroll
    for (int c = 0; c < 2; ++c) {
      const int off = w * 2048 + c * 1024;
      load_lds16(srcA + koff + off + lane * 16, ldsA + off);
      load_lds16(srcB + koff + off + lane * 16, ldsB + off);
    }
    __syncthreads();
    bf16x8 afrag[4], bfrag[4];
#pragma unroll
    for (int i = 0; i < 4; ++i) {
      afrag[i] = *(const bf16x8*)(ldsA + g * 2048 + (wm * 64 + i * 16 + lrow) * 16);
      bfrag[i] = *(const bf16x8*)(ldsB + g * 2048 + (wn * 64 + i * 16 + lrow) * 16);
    }
#pragma unroll
    for (int i = 0; i < 4; ++i)
#pragma unroll
      for (int j = 0; j < 4; ++j)
        acc[i][j] = __builtin_amdgcn_mfma_f32_16x16x32_bf16(afrag[i], bfrag[j], acc[i][j], 0, 0, 0);
    __syncthreads();
  }

  // finalize column inv-norms into LDS (reuse staging LDS; K loop is done)
  float* winv = (float*)lds;
  if (t < 128) {
    float s = 0.f;
#pragma unroll
    for (int k = 0; k < 8; ++k) s += partial[(size_t)k * NT128 + ntile * BN + t];
    winv[t] = 1.f / fmaxf(sqrtf(s), 1e-8f);
  }
  __syncthreads();

  // epilogue: C layout col=lane&15, row=(lane>>4)*4+reg
#pragma unroll
  for (int j = 0; j < 4; ++j) {
    const int cl = wn * 64 + j * 16 + lrow;
    const int col = ntile * BN + cl;
    if (col < CK) {
      const float wv = winv[cl];
#pragma unroll
      for (int i = 0; i < 4; ++i) {
#pragma unroll
        for (int jj = 0; jj < 4; ++jj) {
          const int row = mtile * BM + wm * 64 + i * 16 + g * 4 + jj;
          out[(size_t)row * CK + col] = acc[i][j][jj] * wv;
        }
      }
    }
  }
}

extern "C" void kernel_launch(void* const* d_in, const int* in_sizes, int n_in,
                              void* d_out, int out_size, void* d_ws, size_t ws_size,
                              hipStream_t stream) {
  const float* x = (const float*)d_in[0];
  const float* W = (const float*)d_in[1];
  float* out = (float*)d_out;
  const int Bn = in_sizes[0] / D_DIM;     // 512
  const int CK = in_sizes[1] / D_DIM;     // 17982
  const int ntiles = (CK + BN - 1) / BN;  // 141
  const int mtiles = Bn / BM;             // 4
  const int NT128 = ntiles * BN;          // 18048

  unsigned char* ws = (unsigned char*)d_ws;
  float* partial = (float*)ws;                                     // 8*NT128*4 = 577.5 KB
  unsigned short* An = (unsigned short*)(ws + 655360);             // 512 KB
  unsigned short* Wt = (unsigned short*)(ws + 655360 + (size_t)mtiles * TILE_BYTES);

  hipLaunchKernelGGL(xnorm_kernel, dim3(Bn), dim3(64), 0, stream, x, An);
  hipLaunchKernelGGL(wtrans2_kernel, dim3(ntiles, 8), dim3(256), 0, stream, W, Wt, partial, CK, NT128);
  hipLaunchKernelGGL(gemm_kernel, dim3(ntiles, mtiles), dim3(256), 0, stream, An, Wt, partial, out, CK, NT128);
}